// Round 13
// baseline (618.054 us; speedup 1.0000x reference)
//
#include <hip/hip_runtime.h>

// GCN3: 3x (COO spmm -> Linear(64) -> ReLU), segment-mean pool, softmax head.
// relu(spmm(X)@W + b) == relu(spmm(X@W) + b): dense transform first, then
// PULL-spmm from fp8 Z (e4m3, 64B/row). Edge records 4B: (col<<8)|fp8(val*16).
// spmm: wave = 4 edge-slots x 16 dim-lanes, dword gathers -> 32 lines in
// flight/wave. dense64: W column held in 64 VGPRs per lane (NO LDS — the
// LDS-resident version was ds_read-throughput-bound at 72us), grid-stride
// waves amortize the W load. NT only on full-line bursts (binpass flush).
// CSR build: LDS-staged binpass into 512-row buckets, per-bucket counting sort.

#define BSHIFT 9
#define BROWS  (1 << BSHIFT)   // 512 rows per bucket
#define MAXK   256             // supports N <= 131072
#define CHUNK  6144            // edges per binpass/bhist block

__device__ inline unsigned char f2q(float f) {  // fp8 e4m3 RNE
    unsigned p = __builtin_amdgcn_cvt_pk_fp8_f32(f, f, 0u, false);
    return (unsigned char)(p & 0xffu);
}
template <int SEL>
__device__ inline float q2f(unsigned q) {  // byte-select fp8->f32 (SEL = ICE)
    return __builtin_amdgcn_cvt_f32_fp8(q, SEL);
}

// Per-block LDS histogram of bucket ids -> global bucket counts.
__global__ __launch_bounds__(512) void bhist_k(const int* __restrict__ rows,
                                               int* __restrict__ bhist, int E) {
    __shared__ int h[MAXK];
    int tx = threadIdx.x;
    if (tx < MAXK) h[tx] = 0;
    __syncthreads();
    int e0 = blockIdx.x * CHUNK, ee = min(e0 + CHUNK, E);
    for (int e = e0 + tx; e < ee; e += 512)
        atomicAdd(&h[rows[e] >> BSHIFT], 1);
    __syncthreads();
    if (tx < MAXK && h[tx]) atomicAdd(&bhist[tx], h[tx]);
}

// Exclusive scan of bucket counts (single block); init padded cursors; rp[N]=E.
__global__ __launch_bounds__(MAXK) void bscan_k(const int* __restrict__ bhist,
                                                int* __restrict__ bstart,
                                                int* __restrict__ bcur,
                                                int* __restrict__ rp,
                                                int K, int E, int N) {
    __shared__ int s[MAXK];
    int tx = threadIdx.x;
    int v = (tx < K) ? bhist[tx] : 0;
    s[tx] = v;
    __syncthreads();
    for (int off = 1; off < MAXK; off <<= 1) {
        int t = (tx >= off) ? s[tx - off] : 0;
        __syncthreads();
        s[tx] += t;
        __syncthreads();
    }
    if (tx < K) {
        bstart[tx] = s[tx] - v;
        bcur[tx * 16] = s[tx] - v;  // 1 cursor per 64B line
    }
    if (tx == K - 1) bstart[K] = E;
    if (tx == 0) rp[N] = E;
}

// Bin edges by 512-row bucket, staged in LDS so global writes are ~31-edge
// single-CU bursts. Record (u64): lo32=(col<<9)|(row&511), hi32=val bits.
__global__ __launch_bounds__(512) void binpass_k(
    const int* __restrict__ rows, const int* __restrict__ cols,
    const float* __restrict__ vals, int* __restrict__ bcur,
    unsigned long long* __restrict__ pk, int E) {
    __shared__ int h[MAXK], base[MAXK], gbase[MAXK], lcnt[MAXK];
    __shared__ unsigned long long st[CHUNK];  // 48 KB
    int tx = threadIdx.x;
    if (tx < MAXK) h[tx] = 0;
    __syncthreads();
    int e0 = blockIdx.x * CHUNK, ee = min(e0 + CHUNK, E);
    for (int e = e0 + tx; e < ee; e += 512)
        atomicAdd(&h[rows[e] >> BSHIFT], 1);
    __syncthreads();
    int v = (tx < MAXK) ? h[tx] : 0;
    if (tx < MAXK) lcnt[tx] = v;  // scan buffer
    __syncthreads();
    for (int off = 1; off < MAXK; off <<= 1) {
        int t = (tx >= off && tx < MAXK) ? lcnt[tx - off] : 0;
        __syncthreads();
        if (tx < MAXK) lcnt[tx] += t;
        __syncthreads();
    }
    if (tx < MAXK) {
        base[tx] = lcnt[tx] - v;
        if (v) gbase[tx] = atomicAdd(&bcur[tx * 16], v);
        lcnt[tx] = 0;
    }
    __syncthreads();
    for (int e = e0 + tx; e < ee; e += 512) {
        int r = rows[e];
        int c = cols[e];
        float vv = vals[e];
        int b = r >> BSHIFT;
        int p = base[b] + atomicAdd(&lcnt[b], 1);
        unsigned lo = ((unsigned)c << BSHIFT) | (unsigned)(r & (BROWS - 1));
        st[p] = (unsigned long long)lo
              | ((unsigned long long)(unsigned)__float_as_int(vv) << 32);
    }
    __syncthreads();
    // flush contiguous per-bucket runs, wave-parallel. NT safe: 64 lanes x 8B
    // = 512B contiguous per instruction (full lines covered).
    int lane = tx & 63, wid = tx >> 6;
    for (int b = wid; b < MAXK; b += 8) {
        int cnt = h[b];
        if (!cnt) continue;
        int lb = base[b], gb = gbase[b];
        for (int i = lane; i < cnt; i += 64)
            __builtin_nontemporal_store(st[lb + i], &pk[gb + i]);
    }
}

// Per-bucket counting sort: one block per bucket. LDS hist over 512 rows,
// scan -> rp, then local scatter into the bucket's contiguous epk window.
// CACHED loads/stores (sub-line scatter: L2 must assemble the lines).
// Output record (4B): (col << 8) | fp8(val * 16).
__global__ __launch_bounds__(512) void sort_k(
    const int* __restrict__ bstart, const unsigned long long* __restrict__ pk,
    int* __restrict__ rp, unsigned* __restrict__ epk, int n) {
    __shared__ int hist[BROWS], cur[BROWS];
    int tx = threadIdx.x;
    int b = blockIdx.x;
    int row0 = b << BSHIFT;
    int s = bstart[b], e = bstart[b + 1];
    hist[tx] = 0;
    __syncthreads();
    for (int j = s + tx; j < e; j += 512) {
        unsigned lo = (unsigned)pk[j];
        atomicAdd(&hist[lo & (BROWS - 1)], 1);
    }
    __syncthreads();
    int v = hist[tx];
    for (int off = 1; off < BROWS; off <<= 1) {
        int t = (tx >= off) ? hist[tx - off] : 0;
        __syncthreads();
        hist[tx] += t;
        __syncthreads();
    }
    int excl = hist[tx] - v;
    cur[tx] = excl;
    if (row0 + tx < n) rp[row0 + tx] = s + excl;
    __syncthreads();
    for (int j = s + tx; j < e; j += 512) {
        unsigned long long rec = pk[j];
        unsigned lo = (unsigned)rec;
        float vv = __int_as_float((int)(unsigned)(rec >> 32));
        int r = (int)(lo & (BROWS - 1));
        int q = atomicAdd(&cur[r], 1);
        epk[s + q] = ((lo >> BSHIFT) << 8) | (unsigned)f2q(vv * 16.f);
    }
}

// Zq = fp8(X @ W1), X:[n,5]. Wave per row, lane = out dim.
__global__ __launch_bounds__(256) void dense5_k(
    const float* __restrict__ X, const float* __restrict__ W,
    unsigned char* __restrict__ Zq, int n) {
    int lane = threadIdx.x & 63;
    int row = (blockIdx.x * blockDim.x + threadIdx.x) >> 6;
    if (row >= n) return;
    float w0 = W[lane], w1 = W[64 + lane], w2 = W[128 + lane],
          w3 = W[192 + lane], w4 = W[256 + lane];
    float xv = (lane < 5) ? X[(size_t)row * 5 + lane] : 0.f;
    float y = __shfl(xv, 0, 64) * w0;
    y = fmaf(__shfl(xv, 1, 64), w1, y);
    y = fmaf(__shfl(xv, 2, 64), w2, y);
    y = fmaf(__shfl(xv, 3, 64), w3, y);
    y = fmaf(__shfl(xv, 4, 64), w4, y);
    Zq[(size_t)row * 64 + lane] = f2q(y);
}

// Zq = fp8(X @ W): W column `lane` in 64 VGPRs (no LDS — the LDS version was
// ds_read-throughput-bound at 72us). Grid-stride waves, ~98 rows each, so the
// one-time 64-load W fetch is amortized. Per row: 16 wave-uniform float4
// broadcast loads + 64 fmaf.
__global__ __launch_bounds__(256) void dense64_k(
    const float* __restrict__ X, const float* __restrict__ W,
    unsigned char* __restrict__ Zq, int n) {
    int lane = threadIdx.x & 63, wid = threadIdx.x >> 6;
    float wr[64];
#pragma unroll
    for (int k = 0; k < 64; ++k) wr[k] = W[k * 64 + lane];
    int wave = blockIdx.x * 4 + wid;
    int nw = gridDim.x * 4;
    for (int row = wave; row < n; row += nw) {
        const float4* xr = (const float4*)(X + (size_t)row * 64);
        float y = 0.f;
#pragma unroll
        for (int k4 = 0; k4 < 16; ++k4) {
            float4 xv = xr[k4];  // wave-uniform broadcast
            y = fmaf(xv.x, wr[k4 * 4 + 0], y);
            y = fmaf(xv.y, wr[k4 * 4 + 1], y);
            y = fmaf(xv.z, wr[k4 * 4 + 2], y);
            y = fmaf(xv.w, wr[k4 * 4 + 3], y);
        }
        Zq[(size_t)row * 64 + lane] = f2q(y);
    }
}

// Dword-gather spmm core: wave = 4 edge-slots (lane>>4) x 16 dim-lanes
// (lane&15, 4 dims each). One gather instruction = 4 edge-lines in flight.
// Accumulates t0..t3 (even groups) / u0..u3 (odd); slots folded by shfl_xor.
// Guarded tail uses c=0 (col 0, val fp8 0x00 = 0.0 -> contributes nothing).
#define GATHER_DECL                                                            \
    float t0 = 0.f, t1 = 0.f, t2 = 0.f, t3 = 0.f;                              \
    float u0 = 0.f, u1 = 0.f, u2 = 0.f, u3 = 0.f;

#define GATHER_GROUP(cg, acc0, acc1, acc2, acc3)                               \
    {                                                                          \
        unsigned d = *(const unsigned*)(Zq + (((cg) >> 8) << 6) + (dim4 << 2));\
        float v = q2f<0>((cg));                                                \
        acc0 = fmaf(v, q2f<0>(d), acc0);                                       \
        acc1 = fmaf(v, q2f<1>(d), acc1);                                       \
        acc2 = fmaf(v, q2f<2>(d), acc2);                                       \
        acc3 = fmaf(v, q2f<3>(d), acc3);                                       \
    }

#define GATHER_LOOP(S, E)                                                      \
    GATHER_DECL                                                                \
    int j = (S);                                                               \
    for (; j + 32 <= (E); j += 32) {                                           \
        unsigned c[8];                                                         \
        _Pragma("unroll") for (int g = 0; g < 8; ++g)                          \
            c[g] = epk[j + g * 4 + slot];                                      \
        _Pragma("unroll") for (int g = 0; g < 8; g += 2) {                     \
            GATHER_GROUP(c[g], t0, t1, t2, t3)                                 \
            GATHER_GROUP(c[g + 1], u0, u1, u2, u3)                             \
        }                                                                      \
    }                                                                          \
    for (; j + 4 <= (E); j += 4) {                                             \
        unsigned c = epk[j + slot];                                            \
        GATHER_GROUP(c, t0, t1, t2, t3)                                        \
    }                                                                          \
    if (j < (E)) {                                                             \
        int idx = j + slot;                                                    \
        unsigned c = (idx < (E)) ? epk[idx] : 0u;                              \
        GATHER_GROUP(c, u0, u1, u2, u3)                                        \
    }                                                                          \
    t0 += u0; t1 += u1; t2 += u2; t3 += u3;                                    \
    t0 += __shfl_xor(t0, 16, 64); t1 += __shfl_xor(t1, 16, 64);                \
    t2 += __shfl_xor(t2, 16, 64); t3 += __shfl_xor(t3, 16, 64);                \
    t0 += __shfl_xor(t0, 32, 64); t1 += __shfl_xor(t1, 32, 64);                \
    t2 += __shfl_xor(t2, 32, 64); t3 += __shfl_xor(t3, 32, 64);

// xout[row] = relu(spmm/16 + b). Wave per row.
__global__ __launch_bounds__(256) void spmm_relu_k(
    const int* __restrict__ rp, const unsigned* __restrict__ epk,
    const unsigned char* __restrict__ Zq, const float* __restrict__ bias,
    float* __restrict__ xout, int n) {
    int lane = threadIdx.x & 63;
    int dim4 = lane & 15, slot = lane >> 4;
    int row = (blockIdx.x * blockDim.x + threadIdx.x) >> 6;
    if (row >= n) return;
    GATHER_LOOP(rp[row], rp[row + 1])
    if (slot == 0) {
        float4 bv = ((const float4*)bias)[dim4];
        float4 o;
        o.x = fmaxf(t0 * 0.0625f + bv.x, 0.f);
        o.y = fmaxf(t1 * 0.0625f + bv.y, 0.f);
        o.z = fmaxf(t2 * 0.0625f + bv.z, 0.f);
        o.w = fmaxf(t3 * 0.0625f + bv.w, 0.f);
        ((float4*)(xout + (size_t)row * 64))[dim4] = o;
    }
}

// Layer-3 spmm with fused h = relu(.) + x1 + x2.
__global__ __launch_bounds__(256) void spmm_relu3_k(
    const int* __restrict__ rp, const unsigned* __restrict__ epk,
    const unsigned char* __restrict__ Zq, const float* __restrict__ bias,
    const float* __restrict__ x1, const float* __restrict__ x2,
    float* __restrict__ h, int n) {
    int lane = threadIdx.x & 63;
    int dim4 = lane & 15, slot = lane >> 4;
    int row = (blockIdx.x * blockDim.x + threadIdx.x) >> 6;
    if (row >= n) return;
    GATHER_LOOP(rp[row], rp[row + 1])
    if (slot == 0) {
        float4 bv = ((const float4*)bias)[dim4];
        float4 a = ((const float4*)(x1 + (size_t)row * 64))[dim4];
        float4 b2v = ((const float4*)(x2 + (size_t)row * 64))[dim4];
        float4 o;
        o.x = fmaxf(t0 * 0.0625f + bv.x, 0.f) + a.x + b2v.x;
        o.y = fmaxf(t1 * 0.0625f + bv.y, 0.f) + a.y + b2v.y;
        o.z = fmaxf(t2 * 0.0625f + bv.z, 0.f) + a.z + b2v.z;
        o.w = fmaxf(t3 * 0.0625f + bv.w, 0.f) + a.w + b2v.w;
        ((float4*)(h + (size_t)row * 64))[dim4] = o;
    }
}

// Pool: batch sorted -> run-length accumulate 64 nodes per wave, one
// atomicAdd per segment boundary per lane. h already = x1+x2+x3.
__global__ void pool_k(const float* __restrict__ h, const int* __restrict__ batch,
                       float* __restrict__ sums, int* __restrict__ cnts, int n) {
    int lane = threadIdx.x & 63;
    int w = (blockIdx.x * blockDim.x + threadIdx.x) >> 6;
    int node0 = w * 64;
    if (node0 >= n) return;
    int cur = batch[node0];
    float acc = 0.f;
    int cnt = 0;
    int end = min(node0 + 64, n);
    for (int nd = node0; nd < end; ++nd) {
        int bg = batch[nd];  // wave-uniform
        if (bg != cur) {
            atomicAdd(&sums[(size_t)cur * 64 + lane], acc);
            if (lane == 0) atomicAdd(&cnts[cur], cnt);
            acc = 0.f;
            cnt = 0;
            cur = bg;
        }
        acc += h[(size_t)nd * 64 + lane];
        cnt++;
    }
    atomicAdd(&sums[(size_t)cur * 64 + lane], acc);
    if (lane == 0) atomicAdd(&cnts[cur], cnt);
}

// Head: pooled = sums/(3*cnt); out = softmax(pooled @ Wl + bl). Wave per graph.
__global__ void final_k(const float* __restrict__ sums, const int* __restrict__ cnts,
                        const float* __restrict__ Wl, const float* __restrict__ bl,
                        float* __restrict__ out, int G) {
    int lane = threadIdx.x & 63;
    int g = (blockIdx.x * blockDim.x + threadIdx.x) >> 6;
    if (g >= G) return;
    float c = (float)max(cnts[g], 1);
    float s = sums[(size_t)g * 64 + lane] / (3.f * c);
    float y = (lane < 10) ? bl[lane] : -1e30f;
    for (int k = 0; k < 64; ++k) {
        float sk = __shfl(s, k, 64);
        if (lane < 10) y = fmaf(sk, Wl[k * 10 + lane], y);
    }
    float m = y;
#pragma unroll
    for (int off = 8; off; off >>= 1) m = fmaxf(m, __shfl_xor(m, off, 16));
    float ey = (lane < 10) ? __expf(y - m) : 0.f;
    float sm = ey;
#pragma unroll
    for (int off = 8; off; off >>= 1) sm += __shfl_xor(sm, off, 16);
    if (lane < 10) out[(size_t)g * 10 + lane] = ey / sm;
}

extern "C" void kernel_launch(void* const* d_in, const int* in_sizes, int n_in,
                              void* d_out, int out_size, void* d_ws, size_t ws_size,
                              hipStream_t stream) {
    const float* x = (const float*)d_in[0];
    const int* rows = (const int*)d_in[1];
    const int* cols = (const int*)d_in[2];
    const float* vals = (const float*)d_in[3];
    const int* batch = (const int*)d_in[4];
    const float* W1 = (const float*)d_in[5];
    const float* b1 = (const float*)d_in[6];
    const float* W2 = (const float*)d_in[7];
    const float* b2 = (const float*)d_in[8];
    const float* W3 = (const float*)d_in[9];
    const float* b3 = (const float*)d_in[10];
    const float* Wl = (const float*)d_in[11];
    const float* bl = (const float*)d_in[12];
    float* out = (float*)d_out;

    const int N = in_sizes[4];   // n_nodes (<= 131072)
    const int E = in_sizes[1];   // n_edges
    const int G = out_size / 10; // n_graphs
    const int K = (N + BROWS - 1) >> BSHIFT;

    char* p = (char*)d_ws;
    size_t off = 0;
    auto alloc = [&](size_t bytes) -> void* {
        off = (off + 255) & ~(size_t)255;
        void* r = (void*)(p + off);
        off += bytes;
        return r;
    };
    size_t featF = (size_t)N * 64 * 4;
    int* bhist = (int*)alloc(MAXK * 4);
    int* bstart = (int*)alloc((MAXK + 1) * 4);
    int* bcur = (int*)alloc(MAXK * 16 * 4);
    int* rp = (int*)alloc((size_t)(N + 1) * 4);
    // pk (bucketed, pre-sort) is dead after sort_k; alias with h (written
    // only by the layer-3 spmm, far after sort_k).
    void* regP = alloc((size_t)E * 8 > featF ? (size_t)E * 8 : featF);
    unsigned* epk = (unsigned*)alloc((size_t)E * 4);  // packed sorted edges
    unsigned char* ZqA = (unsigned char*)alloc((size_t)N * 64);
    unsigned char* ZqB = (unsigned char*)alloc((size_t)N * 64);
    float* x1 = (float*)alloc(featF);
    float* x2 = (float*)alloc(featF);
    float* sums = (float*)alloc((size_t)G * 64 * 4);
    int* cnts = (int*)alloc((size_t)G * 4);

    unsigned long long* pk = (unsigned long long*)regP;
    float* h = (float*)regP;

    hipMemsetAsync(bhist, 0, MAXK * 4, stream);
    hipMemsetAsync(sums, 0, (size_t)G * 64 * 4, stream);
    hipMemsetAsync(cnts, 0, (size_t)G * 4, stream);

    int cb = (E + CHUNK - 1) / CHUNK;
    bhist_k<<<cb, 512, 0, stream>>>(rows, bhist, E);
    bscan_k<<<1, MAXK, 0, stream>>>(bhist, bstart, bcur, rp, K, E, N);
    binpass_k<<<cb, 512, 0, stream>>>(rows, cols, vals, bcur, pk, E);
    sort_k<<<K, 512, 0, stream>>>(bstart, pk, rp, epk, N);

    int rb = (N + 3) / 4;  // wave-per-row blocks
    dense5_k<<<rb, 256, 0, stream>>>(x, W1, ZqA, N);
    spmm_relu_k<<<rb, 256, 0, stream>>>(rp, epk, ZqA, b1, x1, N);
    dense64_k<<<256, 256, 0, stream>>>(x1, W2, ZqB, N);
    spmm_relu_k<<<rb, 256, 0, stream>>>(rp, epk, ZqB, b2, x2, N);
    dense64_k<<<256, 256, 0, stream>>>(x2, W3, ZqA, N);
    spmm_relu3_k<<<rb, 256, 0, stream>>>(rp, epk, ZqA, b3, x1, x2, h, N);

    int pw = (N + 63) / 64;
    pool_k<<<(pw + 3) / 4, 256, 0, stream>>>(h, batch, sums, cnts, N);
    final_k<<<(G + 3) / 4, 256, 0, stream>>>(sums, cnts, Wl, bl, out, G);
}

// Round 14
// 547.236 us; speedup vs baseline: 1.1294x; 1.1294x over previous
//
#include <hip/hip_runtime.h>

// GCN3: 3x (COO spmm -> Linear(64) -> ReLU), segment-mean pool, softmax head.
// relu(spmm(X)@W + b) == relu(spmm(X@W) + b): dense transform first, then
// PULL-spmm from fp8 Z (e4m3, 64B/row). Edge records 4B: (col<<8)|fp8(val*16).
// spmm: wave = 4 edge-slots x 16 dim-lanes, dword gathers -> 32 lines in
// flight/wave. dense64: W column in 64 VGPRs/lane (launch_bounds(256,1) so
// the allocator actually keeps them; r13's version without the bound got
// VGPR=40 -> W reloaded per row + 4 waves/CU -> 131us). Grid 1024 blocks =
// 16 waves/CU. NT only on full-line bursts (binpass flush).
// CSR build: LDS-staged binpass into 512-row buckets, per-bucket counting sort.

#define BSHIFT 9
#define BROWS  (1 << BSHIFT)   // 512 rows per bucket
#define MAXK   256             // supports N <= 131072
#define CHUNK  6144            // edges per binpass/bhist block

__device__ inline unsigned char f2q(float f) {  // fp8 e4m3 RNE
    unsigned p = __builtin_amdgcn_cvt_pk_fp8_f32(f, f, 0u, false);
    return (unsigned char)(p & 0xffu);
}
template <int SEL>
__device__ inline float q2f(unsigned q) {  // byte-select fp8->f32 (SEL = ICE)
    return __builtin_amdgcn_cvt_f32_fp8(q, SEL);
}

// Per-block LDS histogram of bucket ids -> global bucket counts.
__global__ __launch_bounds__(512) void bhist_k(const int* __restrict__ rows,
                                               int* __restrict__ bhist, int E) {
    __shared__ int h[MAXK];
    int tx = threadIdx.x;
    if (tx < MAXK) h[tx] = 0;
    __syncthreads();
    int e0 = blockIdx.x * CHUNK, ee = min(e0 + CHUNK, E);
    for (int e = e0 + tx; e < ee; e += 512)
        atomicAdd(&h[rows[e] >> BSHIFT], 1);
    __syncthreads();
    if (tx < MAXK && h[tx]) atomicAdd(&bhist[tx], h[tx]);
}

// Exclusive scan of bucket counts (single block); init padded cursors; rp[N]=E.
__global__ __launch_bounds__(MAXK) void bscan_k(const int* __restrict__ bhist,
                                                int* __restrict__ bstart,
                                                int* __restrict__ bcur,
                                                int* __restrict__ rp,
                                                int K, int E, int N) {
    __shared__ int s[MAXK];
    int tx = threadIdx.x;
    int v = (tx < K) ? bhist[tx] : 0;
    s[tx] = v;
    __syncthreads();
    for (int off = 1; off < MAXK; off <<= 1) {
        int t = (tx >= off) ? s[tx - off] : 0;
        __syncthreads();
        s[tx] += t;
        __syncthreads();
    }
    if (tx < K) {
        bstart[tx] = s[tx] - v;
        bcur[tx * 16] = s[tx] - v;  // 1 cursor per 64B line
    }
    if (tx == K - 1) bstart[K] = E;
    if (tx == 0) rp[N] = E;
}

// Bin edges by 512-row bucket, staged in LDS so global writes are ~31-edge
// single-CU bursts. Record (u64): lo32=(col<<9)|(row&511), hi32=val bits.
__global__ __launch_bounds__(512) void binpass_k(
    const int* __restrict__ rows, const int* __restrict__ cols,
    const float* __restrict__ vals, int* __restrict__ bcur,
    unsigned long long* __restrict__ pk, int E) {
    __shared__ int h[MAXK], base[MAXK], gbase[MAXK], lcnt[MAXK];
    __shared__ unsigned long long st[CHUNK];  // 48 KB
    int tx = threadIdx.x;
    if (tx < MAXK) h[tx] = 0;
    __syncthreads();
    int e0 = blockIdx.x * CHUNK, ee = min(e0 + CHUNK, E);
    for (int e = e0 + tx; e < ee; e += 512)
        atomicAdd(&h[rows[e] >> BSHIFT], 1);
    __syncthreads();
    int v = (tx < MAXK) ? h[tx] : 0;
    if (tx < MAXK) lcnt[tx] = v;  // scan buffer
    __syncthreads();
    for (int off = 1; off < MAXK; off <<= 1) {
        int t = (tx >= off && tx < MAXK) ? lcnt[tx - off] : 0;
        __syncthreads();
        if (tx < MAXK) lcnt[tx] += t;
        __syncthreads();
    }
    if (tx < MAXK) {
        base[tx] = lcnt[tx] - v;
        if (v) gbase[tx] = atomicAdd(&bcur[tx * 16], v);
        lcnt[tx] = 0;
    }
    __syncthreads();
    for (int e = e0 + tx; e < ee; e += 512) {
        int r = rows[e];
        int c = cols[e];
        float vv = vals[e];
        int b = r >> BSHIFT;
        int p = base[b] + atomicAdd(&lcnt[b], 1);
        unsigned lo = ((unsigned)c << BSHIFT) | (unsigned)(r & (BROWS - 1));
        st[p] = (unsigned long long)lo
              | ((unsigned long long)(unsigned)__float_as_int(vv) << 32);
    }
    __syncthreads();
    // flush contiguous per-bucket runs, wave-parallel. NT safe: 64 lanes x 8B
    // = 512B contiguous per instruction (full lines covered).
    int lane = tx & 63, wid = tx >> 6;
    for (int b = wid; b < MAXK; b += 8) {
        int cnt = h[b];
        if (!cnt) continue;
        int lb = base[b], gb = gbase[b];
        for (int i = lane; i < cnt; i += 64)
            __builtin_nontemporal_store(st[lb + i], &pk[gb + i]);
    }
}

// Per-bucket counting sort: one block per bucket. LDS hist over 512 rows,
// scan -> rp, then local scatter into the bucket's contiguous epk window.
// CACHED loads/stores (sub-line scatter: L2 must assemble the lines).
// Output record (4B): (col << 8) | fp8(val * 16).
__global__ __launch_bounds__(512) void sort_k(
    const int* __restrict__ bstart, const unsigned long long* __restrict__ pk,
    int* __restrict__ rp, unsigned* __restrict__ epk, int n) {
    __shared__ int hist[BROWS], cur[BROWS];
    int tx = threadIdx.x;
    int b = blockIdx.x;
    int row0 = b << BSHIFT;
    int s = bstart[b], e = bstart[b + 1];
    hist[tx] = 0;
    __syncthreads();
    for (int j = s + tx; j < e; j += 512) {
        unsigned lo = (unsigned)pk[j];
        atomicAdd(&hist[lo & (BROWS - 1)], 1);
    }
    __syncthreads();
    int v = hist[tx];
    for (int off = 1; off < BROWS; off <<= 1) {
        int t = (tx >= off) ? hist[tx - off] : 0;
        __syncthreads();
        hist[tx] += t;
        __syncthreads();
    }
    int excl = hist[tx] - v;
    cur[tx] = excl;
    if (row0 + tx < n) rp[row0 + tx] = s + excl;
    __syncthreads();
    for (int j = s + tx; j < e; j += 512) {
        unsigned long long rec = pk[j];
        unsigned lo = (unsigned)rec;
        float vv = __int_as_float((int)(unsigned)(rec >> 32));
        int r = (int)(lo & (BROWS - 1));
        int q = atomicAdd(&cur[r], 1);
        epk[s + q] = ((lo >> BSHIFT) << 8) | (unsigned)f2q(vv * 16.f);
    }
}

// Zq = fp8(X @ W1), X:[n,5]. Wave per row, lane = out dim.
__global__ __launch_bounds__(256) void dense5_k(
    const float* __restrict__ X, const float* __restrict__ W,
    unsigned char* __restrict__ Zq, int n) {
    int lane = threadIdx.x & 63;
    int row = (blockIdx.x * blockDim.x + threadIdx.x) >> 6;
    if (row >= n) return;
    float w0 = W[lane], w1 = W[64 + lane], w2 = W[128 + lane],
          w3 = W[192 + lane], w4 = W[256 + lane];
    float xv = (lane < 5) ? X[(size_t)row * 5 + lane] : 0.f;
    float y = __shfl(xv, 0, 64) * w0;
    y = fmaf(__shfl(xv, 1, 64), w1, y);
    y = fmaf(__shfl(xv, 2, 64), w2, y);
    y = fmaf(__shfl(xv, 3, 64), w3, y);
    y = fmaf(__shfl(xv, 4, 64), w4, y);
    Zq[(size_t)row * 64 + lane] = f2q(y);
}

// Zq = fp8(X @ W): W column `lane` in 64 VGPRs. launch_bounds(256,1) lets the
// allocator keep all 64 live (r13 without it: VGPR=40, W reloaded per row).
// Grid 1024 blocks = 4096 waves = 16 waves/CU; ~24 rows/wave amortizes the
// W load to ~2.6 loads/row. Per row: 16 wave-uniform float4 loads + 64 fmaf.
__global__ __launch_bounds__(256, 1) void dense64_k(
    const float* __restrict__ X, const float* __restrict__ W,
    unsigned char* __restrict__ Zq, int n) {
    int lane = threadIdx.x & 63, wid = threadIdx.x >> 6;
    float wr[64];
#pragma unroll
    for (int k = 0; k < 64; ++k) wr[k] = W[k * 64 + lane];
    int wave = blockIdx.x * 4 + wid;
    int nw = gridDim.x * 4;
    for (int row = wave; row < n; row += nw) {
        const float4* xr = (const float4*)(X + (size_t)row * 64);
        float y = 0.f;
#pragma unroll
        for (int k4 = 0; k4 < 16; ++k4) {
            float4 xv = xr[k4];  // wave-uniform broadcast
            y = fmaf(xv.x, wr[k4 * 4 + 0], y);
            y = fmaf(xv.y, wr[k4 * 4 + 1], y);
            y = fmaf(xv.z, wr[k4 * 4 + 2], y);
            y = fmaf(xv.w, wr[k4 * 4 + 3], y);
        }
        Zq[(size_t)row * 64 + lane] = f2q(y);
    }
}

// Dword-gather spmm core: wave = 4 edge-slots (lane>>4) x 16 dim-lanes
// (lane&15, 4 dims each). One gather instruction = 4 edge-lines in flight.
// Accumulates t0..t3 (even groups) / u0..u3 (odd); slots folded by shfl_xor.
// Guarded tail uses c=0 (col 0, val fp8 0x00 = 0.0 -> contributes nothing).
#define GATHER_DECL                                                            \
    float t0 = 0.f, t1 = 0.f, t2 = 0.f, t3 = 0.f;                              \
    float u0 = 0.f, u1 = 0.f, u2 = 0.f, u3 = 0.f;

#define GATHER_GROUP(cg, acc0, acc1, acc2, acc3)                               \
    {                                                                          \
        unsigned d = *(const unsigned*)(Zq + (((cg) >> 8) << 6) + (dim4 << 2));\
        float v = q2f<0>((cg));                                                \
        acc0 = fmaf(v, q2f<0>(d), acc0);                                       \
        acc1 = fmaf(v, q2f<1>(d), acc1);                                       \
        acc2 = fmaf(v, q2f<2>(d), acc2);                                       \
        acc3 = fmaf(v, q2f<3>(d), acc3);                                       \
    }

#define GATHER_LOOP(S, E)                                                      \
    GATHER_DECL                                                                \
    int j = (S);                                                               \
    for (; j + 32 <= (E); j += 32) {                                           \
        unsigned c[8];                                                         \
        _Pragma("unroll") for (int g = 0; g < 8; ++g)                          \
            c[g] = epk[j + g * 4 + slot];                                      \
        _Pragma("unroll") for (int g = 0; g < 8; g += 2) {                     \
            GATHER_GROUP(c[g], t0, t1, t2, t3)                                 \
            GATHER_GROUP(c[g + 1], u0, u1, u2, u3)                             \
        }                                                                      \
    }                                                                          \
    for (; j + 4 <= (E); j += 4) {                                             \
        unsigned c = epk[j + slot];                                            \
        GATHER_GROUP(c, t0, t1, t2, t3)                                        \
    }                                                                          \
    if (j < (E)) {                                                             \
        int idx = j + slot;                                                    \
        unsigned c = (idx < (E)) ? epk[idx] : 0u;                              \
        GATHER_GROUP(c, u0, u1, u2, u3)                                        \
    }                                                                          \
    t0 += u0; t1 += u1; t2 += u2; t3 += u3;                                    \
    t0 += __shfl_xor(t0, 16, 64); t1 += __shfl_xor(t1, 16, 64);                \
    t2 += __shfl_xor(t2, 16, 64); t3 += __shfl_xor(t3, 16, 64);                \
    t0 += __shfl_xor(t0, 32, 64); t1 += __shfl_xor(t1, 32, 64);                \
    t2 += __shfl_xor(t2, 32, 64); t3 += __shfl_xor(t3, 32, 64);

// xout[row] = relu(spmm/16 + b). Wave per row.
__global__ __launch_bounds__(256) void spmm_relu_k(
    const int* __restrict__ rp, const unsigned* __restrict__ epk,
    const unsigned char* __restrict__ Zq, const float* __restrict__ bias,
    float* __restrict__ xout, int n) {
    int lane = threadIdx.x & 63;
    int dim4 = lane & 15, slot = lane >> 4;
    int row = (blockIdx.x * blockDim.x + threadIdx.x) >> 6;
    if (row >= n) return;
    GATHER_LOOP(rp[row], rp[row + 1])
    if (slot == 0) {
        float4 bv = ((const float4*)bias)[dim4];
        float4 o;
        o.x = fmaxf(t0 * 0.0625f + bv.x, 0.f);
        o.y = fmaxf(t1 * 0.0625f + bv.y, 0.f);
        o.z = fmaxf(t2 * 0.0625f + bv.z, 0.f);
        o.w = fmaxf(t3 * 0.0625f + bv.w, 0.f);
        ((float4*)(xout + (size_t)row * 64))[dim4] = o;
    }
}

// Layer-3 spmm with fused h = relu(.) + x1 + x2.
__global__ __launch_bounds__(256) void spmm_relu3_k(
    const int* __restrict__ rp, const unsigned* __restrict__ epk,
    const unsigned char* __restrict__ Zq, const float* __restrict__ bias,
    const float* __restrict__ x1, const float* __restrict__ x2,
    float* __restrict__ h, int n) {
    int lane = threadIdx.x & 63;
    int dim4 = lane & 15, slot = lane >> 4;
    int row = (blockIdx.x * blockDim.x + threadIdx.x) >> 6;
    if (row >= n) return;
    GATHER_LOOP(rp[row], rp[row + 1])
    if (slot == 0) {
        float4 bv = ((const float4*)bias)[dim4];
        float4 a = ((const float4*)(x1 + (size_t)row * 64))[dim4];
        float4 b2v = ((const float4*)(x2 + (size_t)row * 64))[dim4];
        float4 o;
        o.x = fmaxf(t0 * 0.0625f + bv.x, 0.f) + a.x + b2v.x;
        o.y = fmaxf(t1 * 0.0625f + bv.y, 0.f) + a.y + b2v.y;
        o.z = fmaxf(t2 * 0.0625f + bv.z, 0.f) + a.z + b2v.z;
        o.w = fmaxf(t3 * 0.0625f + bv.w, 0.f) + a.w + b2v.w;
        ((float4*)(h + (size_t)row * 64))[dim4] = o;
    }
}

// Pool: batch sorted -> run-length accumulate 64 nodes per wave, one
// atomicAdd per segment boundary per lane. h already = x1+x2+x3.
__global__ void pool_k(const float* __restrict__ h, const int* __restrict__ batch,
                       float* __restrict__ sums, int* __restrict__ cnts, int n) {
    int lane = threadIdx.x & 63;
    int w = (blockIdx.x * blockDim.x + threadIdx.x) >> 6;
    int node0 = w * 64;
    if (node0 >= n) return;
    int cur = batch[node0];
    float acc = 0.f;
    int cnt = 0;
    int end = min(node0 + 64, n);
    for (int nd = node0; nd < end; ++nd) {
        int bg = batch[nd];  // wave-uniform
        if (bg != cur) {
            atomicAdd(&sums[(size_t)cur * 64 + lane], acc);
            if (lane == 0) atomicAdd(&cnts[cur], cnt);
            acc = 0.f;
            cnt = 0;
            cur = bg;
        }
        acc += h[(size_t)nd * 64 + lane];
        cnt++;
    }
    atomicAdd(&sums[(size_t)cur * 64 + lane], acc);
    if (lane == 0) atomicAdd(&cnts[cur], cnt);
}

// Head: pooled = sums/(3*cnt); out = softmax(pooled @ Wl + bl). Wave per graph.
__global__ void final_k(const float* __restrict__ sums, const int* __restrict__ cnts,
                        const float* __restrict__ Wl, const float* __restrict__ bl,
                        float* __restrict__ out, int G) {
    int lane = threadIdx.x & 63;
    int g = (blockIdx.x * blockDim.x + threadIdx.x) >> 6;
    if (g >= G) return;
    float c = (float)max(cnts[g], 1);
    float s = sums[(size_t)g * 64 + lane] / (3.f * c);
    float y = (lane < 10) ? bl[lane] : -1e30f;
    for (int k = 0; k < 64; ++k) {
        float sk = __shfl(s, k, 64);
        if (lane < 10) y = fmaf(sk, Wl[k * 10 + lane], y);
    }
    float m = y;
#pragma unroll
    for (int off = 8; off; off >>= 1) m = fmaxf(m, __shfl_xor(m, off, 16));
    float ey = (lane < 10) ? __expf(y - m) : 0.f;
    float sm = ey;
#pragma unroll
    for (int off = 8; off; off >>= 1) sm += __shfl_xor(sm, off, 16);
    if (lane < 10) out[(size_t)g * 10 + lane] = ey / sm;
}

extern "C" void kernel_launch(void* const* d_in, const int* in_sizes, int n_in,
                              void* d_out, int out_size, void* d_ws, size_t ws_size,
                              hipStream_t stream) {
    const float* x = (const float*)d_in[0];
    const int* rows = (const int*)d_in[1];
    const int* cols = (const int*)d_in[2];
    const float* vals = (const float*)d_in[3];
    const int* batch = (const int*)d_in[4];
    const float* W1 = (const float*)d_in[5];
    const float* b1 = (const float*)d_in[6];
    const float* W2 = (const float*)d_in[7];
    const float* b2 = (const float*)d_in[8];
    const float* W3 = (const float*)d_in[9];
    const float* b3 = (const float*)d_in[10];
    const float* Wl = (const float*)d_in[11];
    const float* bl = (const float*)d_in[12];
    float* out = (float*)d_out;

    const int N = in_sizes[4];   // n_nodes (<= 131072)
    const int E = in_sizes[1];   // n_edges
    const int G = out_size / 10; // n_graphs
    const int K = (N + BROWS - 1) >> BSHIFT;

    char* p = (char*)d_ws;
    size_t off = 0;
    auto alloc = [&](size_t bytes) -> void* {
        off = (off + 255) & ~(size_t)255;
        void* r = (void*)(p + off);
        off += bytes;
        return r;
    };
    size_t featF = (size_t)N * 64 * 4;
    int* bhist = (int*)alloc(MAXK * 4);
    int* bstart = (int*)alloc((MAXK + 1) * 4);
    int* bcur = (int*)alloc(MAXK * 16 * 4);
    int* rp = (int*)alloc((size_t)(N + 1) * 4);
    // pk (bucketed, pre-sort) is dead after sort_k; alias with h (written
    // only by the layer-3 spmm, far after sort_k).
    void* regP = alloc((size_t)E * 8 > featF ? (size_t)E * 8 : featF);
    unsigned* epk = (unsigned*)alloc((size_t)E * 4);  // packed sorted edges
    unsigned char* ZqA = (unsigned char*)alloc((size_t)N * 64);
    unsigned char* ZqB = (unsigned char*)alloc((size_t)N * 64);
    float* x1 = (float*)alloc(featF);
    float* x2 = (float*)alloc(featF);
    float* sums = (float*)alloc((size_t)G * 64 * 4);
    int* cnts = (int*)alloc((size_t)G * 4);

    unsigned long long* pk = (unsigned long long*)regP;
    float* h = (float*)regP;

    hipMemsetAsync(bhist, 0, MAXK * 4, stream);
    hipMemsetAsync(sums, 0, (size_t)G * 64 * 4, stream);
    hipMemsetAsync(cnts, 0, (size_t)G * 4, stream);

    int cb = (E + CHUNK - 1) / CHUNK;
    bhist_k<<<cb, 512, 0, stream>>>(rows, bhist, E);
    bscan_k<<<1, MAXK, 0, stream>>>(bhist, bstart, bcur, rp, K, E, N);
    binpass_k<<<cb, 512, 0, stream>>>(rows, cols, vals, bcur, pk, E);
    sort_k<<<K, 512, 0, stream>>>(bstart, pk, rp, epk, N);

    int rb = (N + 3) / 4;  // wave-per-row blocks
    dense5_k<<<rb, 256, 0, stream>>>(x, W1, ZqA, N);
    spmm_relu_k<<<rb, 256, 0, stream>>>(rp, epk, ZqA, b1, x1, N);
    dense64_k<<<1024, 256, 0, stream>>>(x1, W2, ZqB, N);
    spmm_relu_k<<<rb, 256, 0, stream>>>(rp, epk, ZqB, b2, x2, N);
    dense64_k<<<1024, 256, 0, stream>>>(x2, W3, ZqA, N);
    spmm_relu3_k<<<rb, 256, 0, stream>>>(rp, epk, ZqA, b3, x1, x2, h, N);

    int pw = (N + 63) / 64;
    pool_k<<<(pw + 3) / 4, 256, 0, stream>>>(h, batch, sums, cnts, N);
    final_k<<<(G + 3) / 4, 256, 0, stream>>>(sums, cnts, Wl, bl, out, G);
}